// Round 2
// baseline (515.846 us; speedup 1.0000x reference)
//
#include <hip/hip_runtime.h>
#include <stdint.h>

#define N_NODES 100000
#define N_EDGES 1600000
#define D_FEAT  512
#define HIDDEN  64
#define N_CLASS 16

// ---------------- threefry2x32-20, key = (0, 42)  (jax.random.key(42)) ------
__device__ __forceinline__ unsigned rotl32(unsigned x, int d) {
    return (x << d) | (x >> (32 - d));
}
__device__ __forceinline__ void tf_round(unsigned& x0, unsigned& x1, int r) {
    x0 += x1; x1 = rotl32(x1, r); x1 ^= x0;
}
__device__ __forceinline__ uint2 threefry_0_42(unsigned c0, unsigned c1) {
    const unsigned ks0 = 0u, ks1 = 42u, ks2 = 0x1BD11BDAu ^ 0u ^ 42u; // 0x1BD11BF0
    unsigned x0 = c0 + ks0, x1 = c1 + ks1;
    tf_round(x0,x1,13); tf_round(x0,x1,15); tf_round(x0,x1,26); tf_round(x0,x1,6);
    x0 += ks1; x1 += ks2 + 1u;
    tf_round(x0,x1,17); tf_round(x0,x1,29); tf_round(x0,x1,16); tf_round(x0,x1,24);
    x0 += ks2; x1 += ks0 + 2u;
    tf_round(x0,x1,13); tf_round(x0,x1,15); tf_round(x0,x1,26); tf_round(x0,x1,6);
    x0 += ks0; x1 += ks1 + 3u;
    tf_round(x0,x1,17); tf_round(x0,x1,29); tf_round(x0,x1,16); tf_round(x0,x1,24);
    x0 += ks1; x1 += ks2 + 4u;
    tf_round(x0,x1,13); tf_round(x0,x1,15); tf_round(x0,x1,26); tf_round(x0,x1,6);
    x0 += ks2; x1 += ks0 + 5u;
    return make_uint2(x0, x1);
}

// ---------------- CSR build ------------------------------------------------
__global__ void k_hist(const int* __restrict__ dst, const float* __restrict__ w,
                       float* __restrict__ deg, int* __restrict__ counts) {
    int e = blockIdx.x * blockDim.x + threadIdx.x;
    if (e < N_EDGES) {
        int d = dst[e];
        atomicAdd(&deg[d], w[e]);
        atomicAdd(&counts[d], 1);
    }
}

// deg -> dis = rsqrt(deg + 1)  (self-loop weight 1; deg>=1 so no zero guard)
__global__ void k_dis(float* __restrict__ deg_dis) {
    int i = blockIdx.x * blockDim.x + threadIdx.x;
    if (i < N_NODES) deg_dis[i] = rsqrtf(deg_dis[i] + 1.0f);
}

#define CHUNK 1024
#define NCHUNK 98   // ceil(100000/1024)

__global__ void k_chunksum(const int* __restrict__ counts, int* __restrict__ bsum) {
    __shared__ int sh[256];
    int b = blockIdx.x, tid = threadIdx.x;
    int base = b * CHUNK + tid * 4;
    int s = 0;
    #pragma unroll
    for (int t = 0; t < 4; t++) {
        int i = base + t;
        if (i < N_NODES) s += counts[i];
    }
    sh[tid] = s; __syncthreads();
    for (int o = 128; o > 0; o >>= 1) {
        if (tid < o) sh[tid] += sh[tid + o];
        __syncthreads();
    }
    if (tid == 0) bsum[b] = sh[0];
}

__global__ void k_scanb(const int* __restrict__ bsum, int* __restrict__ boff) {
    if (threadIdx.x == 0) {
        int run = 0;
        for (int b = 0; b < NCHUNK; b++) { boff[b] = run; run += bsum[b]; }
    }
}

__global__ void k_offsets(const int* __restrict__ counts, const int* __restrict__ boff,
                          int* __restrict__ offs, int* __restrict__ cursor) {
    __shared__ int sh[256];
    int b = blockIdx.x, tid = threadIdx.x;
    int base = b * CHUNK + tid * 4;
    int c[4]; int s = 0;
    #pragma unroll
    for (int t = 0; t < 4; t++) {
        c[t] = (base + t < N_NODES) ? counts[base + t] : 0;
        s += c[t];
    }
    sh[tid] = s; __syncthreads();
    for (int o = 1; o < 256; o <<= 1) {
        int v = (tid >= o) ? sh[tid - o] : 0;
        __syncthreads();
        sh[tid] += v;
        __syncthreads();
    }
    int excl = sh[tid] - s + boff[b];
    #pragma unroll
    for (int t = 0; t < 4; t++) {
        int i = base + t;
        if (i < N_NODES) { offs[i] = excl; cursor[i] = excl; }
        excl += c[t];
    }
}

__global__ void k_scatter(const int* __restrict__ src, const int* __restrict__ dst,
                          const float* __restrict__ w, const float* __restrict__ dis,
                          int* __restrict__ cursor,
                          int* __restrict__ csr_s, float* __restrict__ csr_n) {
    int e = blockIdx.x * blockDim.x + threadIdx.x;
    if (e < N_EDGES) {
        int s = src[e], d = dst[e];
        int pos = atomicAdd(&cursor[d], 1);
        csr_s[pos] = s;
        csr_n[pos] = dis[s] * w[e] * dis[d];
    }
}

// ---------------- GEMM1: h1[100000,64] = x[100000,512] @ W1[512,64] (fp32) --
__launch_bounds__(256)
__global__ void k_gemm1(const float* __restrict__ x, const float* __restrict__ W1,
                        float* __restrict__ h1) {
    __shared__ float As[128][17];   // +1 pad -> conflict-free column reads
    __shared__ float Ws[16][64];
    int tid = threadIdx.x;
    int brow = blockIdx.x * 128;
    int r0 = (tid >> 3) << 2;       // 0..124 step 4
    int c0 = (tid & 7) << 3;        // 0..56 step 8
    float acc[4][8];
    #pragma unroll
    for (int i = 0; i < 4; i++)
        #pragma unroll
        for (int j = 0; j < 8; j++) acc[i][j] = 0.f;

    for (int k0 = 0; k0 < D_FEAT; k0 += 16) {
        // stage A: 128 rows x 16 cols, 2 float4 per thread
        #pragma unroll
        for (int t = 0; t < 2; t++) {
            int fidx = tid + 256 * t;
            int r = fidx >> 2, c4 = (fidx & 3) << 2;
            int grow = brow + r;
            float4 v = make_float4(0.f, 0.f, 0.f, 0.f);
            if (grow < N_NODES)
                v = *(const float4*)&x[(size_t)grow * D_FEAT + k0 + c4];
            As[r][c4 + 0] = v.x; As[r][c4 + 1] = v.y;
            As[r][c4 + 2] = v.z; As[r][c4 + 3] = v.w;
        }
        // stage W: 16 x 64, 1 float4 per thread
        {
            int kk = tid >> 4, c4 = (tid & 15) << 2;
            float4 v = *(const float4*)&W1[(size_t)(k0 + kk) * HIDDEN + c4];
            *(float4*)&Ws[kk][c4] = v;
        }
        __syncthreads();
        #pragma unroll
        for (int kk = 0; kk < 16; kk++) {
            float a0 = As[r0 + 0][kk], a1 = As[r0 + 1][kk];
            float a2 = As[r0 + 2][kk], a3 = As[r0 + 3][kk];
            float4 w0 = *(float4*)&Ws[kk][c0];
            float4 w1 = *(float4*)&Ws[kk][c0 + 4];
            float wv[8] = {w0.x, w0.y, w0.z, w0.w, w1.x, w1.y, w1.z, w1.w};
            #pragma unroll
            for (int j = 0; j < 8; j++) {
                acc[0][j] += a0 * wv[j];
                acc[1][j] += a1 * wv[j];
                acc[2][j] += a2 * wv[j];
                acc[3][j] += a3 * wv[j];
            }
        }
        __syncthreads();
    }
    #pragma unroll
    for (int i = 0; i < 4; i++) {
        int grow = brow + r0 + i;
        if (grow < N_NODES) {
            float4 s0 = make_float4(acc[i][0], acc[i][1], acc[i][2], acc[i][3]);
            float4 s1 = make_float4(acc[i][4], acc[i][5], acc[i][6], acc[i][7]);
            *(float4*)&h1[(size_t)grow * HIDDEN + c0] = s0;
            *(float4*)&h1[(size_t)grow * HIDDEN + c0 + 4] = s1;
        }
    }
}

// ---------------- agg1 + bias + relu + exact-jax dropout --------------------
// Dropout mask matches jax_threefry_partitionable=True (default in modern JAX):
// bits[idx] = x0 ^ x1 of threefry2x32(key=(0,42), counter=(idx>>32, idx&0xffffffff));
// keep iff uniform<0.5 iff MSB(bits)==0.
__launch_bounds__(256)
__global__ void k_agg1(const float* __restrict__ h1, const int* __restrict__ csr_s,
                       const float* __restrict__ csr_n, const int* __restrict__ offs,
                       const int* __restrict__ counts, const float* __restrict__ dis,
                       const float* __restrict__ b1, float* __restrict__ h2) {
    int wid = (blockIdx.x * blockDim.x + threadIdx.x) >> 6;  // node id
    int f = threadIdx.x & 63;
    if (wid >= N_NODES) return;
    int i = wid;
    float di = dis[i];
    float acc = di * di * h1[(size_t)i * HIDDEN + f];   // self loop (w=1)
    int p = offs[i];
    int e = p + counts[i];
    for (; p + 4 <= e; p += 4) {
        int   s0 = csr_s[p],   s1 = csr_s[p+1], s2 = csr_s[p+2], s3 = csr_s[p+3];
        float n0 = csr_n[p],   n1 = csr_n[p+1], n2 = csr_n[p+2], n3 = csr_n[p+3];
        float v0 = h1[(size_t)s0 * HIDDEN + f];
        float v1 = h1[(size_t)s1 * HIDDEN + f];
        float v2 = h1[(size_t)s2 * HIDDEN + f];
        float v3 = h1[(size_t)s3 * HIDDEN + f];
        acc += n0 * v0 + n1 * v1 + n2 * v2 + n3 * v3;
    }
    for (; p < e; ++p)
        acc += csr_n[p] * h1[(size_t)csr_s[p] * HIDDEN + f];
    acc += b1[f];
    acc = fmaxf(acc, 0.f);
    unsigned idx = (unsigned)i * HIDDEN + f;
    uint2 r = threefry_0_42(0u, idx);
    unsigned bits = r.x ^ r.y;
    float v = (bits & 0x80000000u) ? 0.f : acc * 2.f;
    h2[(size_t)i * HIDDEN + f] = v;
}

// ---------------- GEMM2: g[100000,16] = h2 @ W2[64,16] ----------------------
__launch_bounds__(256)
__global__ void k_gemm2(const float* __restrict__ h2, const float* __restrict__ W2,
                        float* __restrict__ g) {
    __shared__ float Ws[HIDDEN * N_CLASS];   // 1024 floats
    int tid = threadIdx.x;
    #pragma unroll
    for (int t = 0; t < 4; t++) Ws[tid + 256 * t] = W2[tid + 256 * t];
    __syncthreads();
    int node = blockIdx.x * 16 + (tid >> 4);
    int j = tid & 15;
    if (node < N_NODES) {
        const float* hr = &h2[(size_t)node * HIDDEN];
        float acc = 0.f;
        #pragma unroll
        for (int f = 0; f < HIDDEN; f++) acc += hr[f] * Ws[f * N_CLASS + j];
        g[(size_t)node * N_CLASS + j] = acc;
    }
}

// ---------------- agg2 + bias + log_softmax + both outputs ------------------
__launch_bounds__(256)
__global__ void k_out(const float* __restrict__ g, const int* __restrict__ csr_s,
                      const float* __restrict__ csr_n, const int* __restrict__ offs,
                      const int* __restrict__ counts, const float* __restrict__ dis,
                      const float* __restrict__ b2, float* __restrict__ out) {
    int sub = (blockIdx.x * blockDim.x + threadIdx.x) >> 4;  // node id
    int j = threadIdx.x & 15;
    if (sub >= N_NODES) return;
    int i = sub;
    float di = dis[i];
    float acc = di * di * g[(size_t)i * N_CLASS + j];
    int p = offs[i];
    int e = p + counts[i];
    for (; p + 2 <= e; p += 2) {
        int   s0 = csr_s[p], s1 = csr_s[p+1];
        float n0 = csr_n[p], n1 = csr_n[p+1];
        acc += n0 * g[(size_t)s0 * N_CLASS + j] + n1 * g[(size_t)s1 * N_CLASS + j];
    }
    for (; p < e; ++p)
        acc += csr_n[p] * g[(size_t)csr_s[p] * N_CLASS + j];
    acc += b2[j];
    float xo = acc;
    float m = acc;
    #pragma unroll
    for (int d = 1; d < 16; d <<= 1) m = fmaxf(m, __shfl_xor(m, d, 16));
    float ex = expf(acc - m);
    float s = ex;
    #pragma unroll
    for (int d = 1; d < 16; d <<= 1) s += __shfl_xor(s, d, 16);
    float ls = (acc - m) - logf(s);
    out[(size_t)i * N_CLASS + j] = ls;
    out[(size_t)N_NODES * N_CLASS + (size_t)i * N_CLASS + j] = xo;
}

// ---------------------------------------------------------------------------
extern "C" void kernel_launch(void* const* d_in, const int* in_sizes, int n_in,
                              void* d_out, int out_size, void* d_ws, size_t ws_size,
                              hipStream_t stream) {
    const float* x  = (const float*)d_in[0];
    const int*   ei = (const int*)d_in[1];
    const float* ew = (const float*)d_in[2];
    const float* W1 = (const float*)d_in[3];
    const float* b1 = (const float*)d_in[4];
    const float* W2 = (const float*)d_in[5];
    const float* b2 = (const float*)d_in[6];
    float* out = (float*)d_out;
    const int* src = ei;
    const int* dst = ei + N_EDGES;

    size_t off = 0;
    char* wsb = (char*)d_ws;
    auto alloc = [&](size_t n) -> char* {
        char* p = wsb + off;
        off = (off + n + 255) & ~(size_t)255;
        return p;
    };
    float* dis    = (float*)alloc((size_t)N_NODES * 4);   // deg, then dis in place
    int*   counts = (int*)  alloc((size_t)N_NODES * 4);
    int*   offs   = (int*)  alloc((size_t)N_NODES * 4);
    int*   cursor = (int*)  alloc((size_t)N_NODES * 4);
    int*   bsum   = (int*)  alloc(128 * 4);
    int*   boff   = (int*)  alloc(128 * 4);
    int*   csr_s  = (int*)  alloc((size_t)N_EDGES * 4);
    float* csr_n  = (float*)alloc((size_t)N_EDGES * 4);
    float* h1     = (float*)alloc((size_t)N_NODES * HIDDEN * 4);
    float* h2     = (float*)alloc((size_t)N_NODES * HIDDEN * 4);
    float* g      = (float*)alloc((size_t)N_NODES * N_CLASS * 4);

    hipMemsetAsync(dis, 0, (size_t)N_NODES * 4, stream);
    hipMemsetAsync(counts, 0, (size_t)N_NODES * 4, stream);

    k_hist    <<<(N_EDGES + 255) / 256, 256, 0, stream>>>(dst, ew, dis, counts);
    k_dis     <<<(N_NODES + 255) / 256, 256, 0, stream>>>(dis);
    k_chunksum<<<NCHUNK, 256, 0, stream>>>(counts, bsum);
    k_scanb   <<<1, 64, 0, stream>>>(bsum, boff);
    k_offsets <<<NCHUNK, 256, 0, stream>>>(counts, boff, offs, cursor);
    k_scatter <<<(N_EDGES + 255) / 256, 256, 0, stream>>>(src, dst, ew, dis, cursor, csr_s, csr_n);
    k_gemm1   <<<(N_NODES + 127) / 128, 256, 0, stream>>>(x, W1, h1);
    k_agg1    <<<(N_NODES * 64 + 255) / 256, 256, 0, stream>>>(h1, csr_s, csr_n, offs, counts, dis, b1, h2);
    k_gemm2   <<<(N_NODES + 15) / 16, 256, 0, stream>>>(h2, W2, g);
    k_out     <<<(N_NODES * 16 + 255) / 256, 256, 0, stream>>>(g, csr_s, csr_n, offs, counts, dis, b2, out);
}

// Round 3
// 374.482 us; speedup vs baseline: 1.3775x; 1.3775x over previous
//
#include <hip/hip_runtime.h>
#include <stdint.h>

#define N_NODES 100000
#define N_EDGES 1600000
#define D_FEAT  512
#define HIDDEN  64
#define N_CLASS 16
#define CAP     64          // fixed slot capacity per node (max in-deg ~45)

// ---------------- threefry2x32-20, key = (0, 42)  (jax.random.key(42)) ------
__device__ __forceinline__ unsigned rotl32(unsigned x, int d) {
    return (x << d) | (x >> (32 - d));
}
__device__ __forceinline__ void tf_round(unsigned& x0, unsigned& x1, int r) {
    x0 += x1; x1 = rotl32(x1, r); x1 ^= x0;
}
__device__ __forceinline__ uint2 threefry_0_42(unsigned c0, unsigned c1) {
    const unsigned ks0 = 0u, ks1 = 42u, ks2 = 0x1BD11BDAu ^ 0u ^ 42u;
    unsigned x0 = c0 + ks0, x1 = c1 + ks1;
    tf_round(x0,x1,13); tf_round(x0,x1,15); tf_round(x0,x1,26); tf_round(x0,x1,6);
    x0 += ks1; x1 += ks2 + 1u;
    tf_round(x0,x1,17); tf_round(x0,x1,29); tf_round(x0,x1,16); tf_round(x0,x1,24);
    x0 += ks2; x1 += ks0 + 2u;
    tf_round(x0,x1,13); tf_round(x0,x1,15); tf_round(x0,x1,26); tf_round(x0,x1,6);
    x0 += ks0; x1 += ks1 + 3u;
    tf_round(x0,x1,17); tf_round(x0,x1,29); tf_round(x0,x1,16); tf_round(x0,x1,24);
    x0 += ks1; x1 += ks2 + 4u;
    tf_round(x0,x1,13); tf_round(x0,x1,15); tf_round(x0,x1,26); tf_round(x0,x1,6);
    x0 += ks2; x1 += ks0 + 5u;
    return make_uint2(x0, x1);
}

// ---- slot-direct scatter: one int atomic + one 8B store per edge ----------
__global__ void k_scatter_direct(const int* __restrict__ src, const int* __restrict__ dst,
                                 const float* __restrict__ w,
                                 int* __restrict__ cursor, int2* __restrict__ slots) {
    int e = blockIdx.x * blockDim.x + threadIdx.x;
    if (e < N_EDGES) {
        int d = dst[e];
        int pos = atomicAdd(&cursor[d], 1);
        if (pos < CAP)
            slots[((size_t)d << 6) + pos] = make_int2(src[e], __float_as_int(w[e]));
    }
}

// ---- deg + dis: wave per node, segmented reduce over slots ----------------
__launch_bounds__(256)
__global__ void k_deg(const int* __restrict__ cursor, const int2* __restrict__ slots,
                      float* __restrict__ dis) {
    int node = (blockIdx.x * blockDim.x + threadIdx.x) >> 6;
    int lane = threadIdx.x & 63;
    if (node >= N_NODES) return;
    int cnt = cursor[node]; cnt = cnt > CAP ? CAP : cnt;
    float wv = 0.f;
    if (lane < cnt) wv = __int_as_float(slots[((size_t)node << 6) + lane].y);
    #pragma unroll
    for (int d = 1; d < 64; d <<= 1) wv += __shfl_xor(wv, d, 64);
    if (lane == 0) dis[node] = rsqrtf(wv + 1.0f);   // +1 = self-loop weight
}

// ---------------- GEMM1: h1[100000,64] = x[100000,512] @ W1[512,64] (fp32) --
__launch_bounds__(256)
__global__ void k_gemm1(const float* __restrict__ x, const float* __restrict__ W1,
                        float* __restrict__ h1) {
    __shared__ float As[128][17];
    __shared__ float Ws[16][64];
    int tid = threadIdx.x;
    int brow = blockIdx.x * 128;
    int r0 = (tid >> 3) << 2;
    int c0 = (tid & 7) << 3;
    float acc[4][8];
    #pragma unroll
    for (int i = 0; i < 4; i++)
        #pragma unroll
        for (int j = 0; j < 8; j++) acc[i][j] = 0.f;

    for (int k0 = 0; k0 < D_FEAT; k0 += 16) {
        #pragma unroll
        for (int t = 0; t < 2; t++) {
            int fidx = tid + 256 * t;
            int r = fidx >> 2, c4 = (fidx & 3) << 2;
            int grow = brow + r;
            float4 v = make_float4(0.f, 0.f, 0.f, 0.f);
            if (grow < N_NODES)
                v = *(const float4*)&x[(size_t)grow * D_FEAT + k0 + c4];
            As[r][c4 + 0] = v.x; As[r][c4 + 1] = v.y;
            As[r][c4 + 2] = v.z; As[r][c4 + 3] = v.w;
        }
        {
            int kk = tid >> 4, c4 = (tid & 15) << 2;
            float4 v = *(const float4*)&W1[(size_t)(k0 + kk) * HIDDEN + c4];
            *(float4*)&Ws[kk][c4] = v;
        }
        __syncthreads();
        #pragma unroll
        for (int kk = 0; kk < 16; kk++) {
            float a0 = As[r0 + 0][kk], a1 = As[r0 + 1][kk];
            float a2 = As[r0 + 2][kk], a3 = As[r0 + 3][kk];
            float4 w0 = *(float4*)&Ws[kk][c0];
            float4 w1 = *(float4*)&Ws[kk][c0 + 4];
            float wv[8] = {w0.x, w0.y, w0.z, w0.w, w1.x, w1.y, w1.z, w1.w};
            #pragma unroll
            for (int j = 0; j < 8; j++) {
                acc[0][j] += a0 * wv[j];
                acc[1][j] += a1 * wv[j];
                acc[2][j] += a2 * wv[j];
                acc[3][j] += a3 * wv[j];
            }
        }
        __syncthreads();
    }
    #pragma unroll
    for (int i = 0; i < 4; i++) {
        int grow = brow + r0 + i;
        if (grow < N_NODES) {
            float4 s0 = make_float4(acc[i][0], acc[i][1], acc[i][2], acc[i][3]);
            float4 s1 = make_float4(acc[i][4], acc[i][5], acc[i][6], acc[i][7]);
            *(float4*)&h1[(size_t)grow * HIDDEN + c0] = s0;
            *(float4*)&h1[(size_t)grow * HIDDEN + c0 + 4] = s1;
        }
    }
}

// ---- agg1 + bias + relu + exact-jax dropout (partitionable threefry) ------
__launch_bounds__(256)
__global__ void k_agg1(const float* __restrict__ h1, const int2* __restrict__ slots,
                       const int* __restrict__ cursor, const float* __restrict__ dis,
                       const float* __restrict__ b1, float* __restrict__ h2) {
    int i = (blockIdx.x * blockDim.x + threadIdx.x) >> 6;  // node id
    int f = threadIdx.x & 63;
    if (i >= N_NODES) return;
    float di = dis[i];
    float acc = di * di * h1[(size_t)i * HIDDEN + f];      // self loop (w=1)
    int cnt = cursor[i]; cnt = cnt > CAP ? CAP : cnt;
    const int2* sl = &slots[(size_t)i << 6];
    int p = 0;
    for (; p + 4 <= cnt; p += 4) {
        int2 e0 = sl[p], e1 = sl[p+1], e2 = sl[p+2], e3 = sl[p+3];
        float n0 = dis[e0.x] * __int_as_float(e0.y) * di;
        float n1 = dis[e1.x] * __int_as_float(e1.y) * di;
        float n2 = dis[e2.x] * __int_as_float(e2.y) * di;
        float n3 = dis[e3.x] * __int_as_float(e3.y) * di;
        float v0 = h1[(size_t)e0.x * HIDDEN + f];
        float v1 = h1[(size_t)e1.x * HIDDEN + f];
        float v2 = h1[(size_t)e2.x * HIDDEN + f];
        float v3 = h1[(size_t)e3.x * HIDDEN + f];
        acc += n0 * v0 + n1 * v1 + n2 * v2 + n3 * v3;
    }
    for (; p < cnt; ++p) {
        int2 e0 = sl[p];
        acc += dis[e0.x] * __int_as_float(e0.y) * di * h1[(size_t)e0.x * HIDDEN + f];
    }
    acc += b1[f];
    acc = fmaxf(acc, 0.f);
    // dropout: partitionable threefry, counter (0, idx), bits = x0^x1, keep iff MSB==0
    unsigned idx = (unsigned)i * HIDDEN + f;
    uint2 r = threefry_0_42(0u, idx);
    unsigned bits = r.x ^ r.y;
    float v = (bits & 0x80000000u) ? 0.f : acc * 2.f;
    h2[(size_t)i * HIDDEN + f] = v;
}

// ---------------- GEMM2: g[100000,16] = h2 @ W2[64,16] ----------------------
__launch_bounds__(256)
__global__ void k_gemm2(const float* __restrict__ h2, const float* __restrict__ W2,
                        float* __restrict__ g) {
    __shared__ float Ws[HIDDEN * N_CLASS];
    int tid = threadIdx.x;
    #pragma unroll
    for (int t = 0; t < 4; t++) Ws[tid + 256 * t] = W2[tid + 256 * t];
    __syncthreads();
    int node = blockIdx.x * 16 + (tid >> 4);
    int j = tid & 15;
    if (node < N_NODES) {
        const float* hr = &h2[(size_t)node * HIDDEN];
        float acc = 0.f;
        #pragma unroll
        for (int f = 0; f < HIDDEN; f++) acc += hr[f] * Ws[f * N_CLASS + j];
        g[(size_t)node * N_CLASS + j] = acc;
    }
}

// ---- agg2 + bias + log_softmax + both outputs -----------------------------
__launch_bounds__(256)
__global__ void k_out(const float* __restrict__ g, const int2* __restrict__ slots,
                      const int* __restrict__ cursor, const float* __restrict__ dis,
                      const float* __restrict__ b2, float* __restrict__ out) {
    int i = (blockIdx.x * blockDim.x + threadIdx.x) >> 4;  // node id
    int j = threadIdx.x & 15;
    if (i >= N_NODES) return;
    float di = dis[i];
    float acc = di * di * g[(size_t)i * N_CLASS + j];
    int cnt = cursor[i]; cnt = cnt > CAP ? CAP : cnt;
    const int2* sl = &slots[(size_t)i << 6];
    int p = 0;
    for (; p + 2 <= cnt; p += 2) {
        int2 e0 = sl[p], e1 = sl[p+1];
        float n0 = dis[e0.x] * __int_as_float(e0.y) * di;
        float n1 = dis[e1.x] * __int_as_float(e1.y) * di;
        acc += n0 * g[(size_t)e0.x * N_CLASS + j] + n1 * g[(size_t)e1.x * N_CLASS + j];
    }
    for (; p < cnt; ++p) {
        int2 e0 = sl[p];
        acc += dis[e0.x] * __int_as_float(e0.y) * di * g[(size_t)e0.x * N_CLASS + j];
    }
    acc += b2[j];
    float xo = acc;
    float m = acc;
    #pragma unroll
    for (int d = 1; d < 16; d <<= 1) m = fmaxf(m, __shfl_xor(m, d, 16));
    float ex = expf(acc - m);
    float s = ex;
    #pragma unroll
    for (int d = 1; d < 16; d <<= 1) s += __shfl_xor(s, d, 16);
    float ls = (acc - m) - logf(s);
    out[(size_t)i * N_CLASS + j] = ls;
    out[(size_t)N_NODES * N_CLASS + (size_t)i * N_CLASS + j] = xo;
}

// ---------------------------------------------------------------------------
extern "C" void kernel_launch(void* const* d_in, const int* in_sizes, int n_in,
                              void* d_out, int out_size, void* d_ws, size_t ws_size,
                              hipStream_t stream) {
    const float* x  = (const float*)d_in[0];
    const int*   ei = (const int*)d_in[1];
    const float* ew = (const float*)d_in[2];
    const float* W1 = (const float*)d_in[3];
    const float* b1 = (const float*)d_in[4];
    const float* W2 = (const float*)d_in[5];
    const float* b2 = (const float*)d_in[6];
    float* out = (float*)d_out;
    const int* src = ei;
    const int* dst = ei + N_EDGES;

    size_t off = 0;
    char* wsb = (char*)d_ws;
    auto alloc = [&](size_t n) -> char* {
        char* p = wsb + off;
        off = (off + n + 255) & ~(size_t)255;
        return p;
    };
    int*   cursor = (int*)  alloc((size_t)N_NODES * 4);
    float* dis    = (float*)alloc((size_t)N_NODES * 4);
    int2*  slots  = (int2*) alloc((size_t)N_NODES * CAP * 8);   // 51.2 MB
    float* h1     = (float*)alloc((size_t)N_NODES * HIDDEN * 4);
    float* h2     = (float*)alloc((size_t)N_NODES * HIDDEN * 4);
    float* g      = (float*)alloc((size_t)N_NODES * N_CLASS * 4);

    hipMemsetAsync(cursor, 0, (size_t)N_NODES * 4, stream);

    k_scatter_direct<<<(N_EDGES + 255) / 256, 256, 0, stream>>>(src, dst, ew, cursor, slots);
    k_deg  <<<(N_NODES * 64 + 255) / 256, 256, 0, stream>>>(cursor, slots, dis);
    k_gemm1<<<(N_NODES + 127) / 128, 256, 0, stream>>>(x, W1, h1);
    k_agg1 <<<(N_NODES * 64 + 255) / 256, 256, 0, stream>>>(h1, slots, cursor, dis, b1, h2);
    k_gemm2<<<(N_NODES + 15) / 16, 256, 0, stream>>>(h2, W2, g);
    k_out  <<<(N_NODES * 16 + 255) / 256, 256, 0, stream>>>(g, slots, cursor, dis, b2, out);
}

// Round 4
// 323.382 us; speedup vs baseline: 1.5952x; 1.1580x over previous
//
#include <hip/hip_runtime.h>
#include <stdint.h>

#define N_NODES 100000
#define N_EDGES 1600000
#define D_FEAT  512
#define HIDDEN  64
#define N_CLASS 16
#define CAP     64          // fixed slot capacity per node (max in-deg ~45)

typedef __bf16 bf16_t;
typedef bf16_t bf16x8 __attribute__((ext_vector_type(8)));
typedef float  f32x4  __attribute__((ext_vector_type(4)));

// ---------------- threefry2x32-20, key = (0, 42)  (jax.random.key(42)) ------
__device__ __forceinline__ unsigned rotl32(unsigned x, int d) {
    return (x << d) | (x >> (32 - d));
}
__device__ __forceinline__ void tf_round(unsigned& x0, unsigned& x1, int r) {
    x0 += x1; x1 = rotl32(x1, r); x1 ^= x0;
}
__device__ __forceinline__ uint2 threefry_0_42(unsigned c0, unsigned c1) {
    const unsigned ks0 = 0u, ks1 = 42u, ks2 = 0x1BD11BDAu ^ 0u ^ 42u;
    unsigned x0 = c0 + ks0, x1 = c1 + ks1;
    tf_round(x0,x1,13); tf_round(x0,x1,15); tf_round(x0,x1,26); tf_round(x0,x1,6);
    x0 += ks1; x1 += ks2 + 1u;
    tf_round(x0,x1,17); tf_round(x0,x1,29); tf_round(x0,x1,16); tf_round(x0,x1,24);
    x0 += ks2; x1 += ks0 + 2u;
    tf_round(x0,x1,13); tf_round(x0,x1,15); tf_round(x0,x1,26); tf_round(x0,x1,6);
    x0 += ks0; x1 += ks1 + 3u;
    tf_round(x0,x1,17); tf_round(x0,x1,29); tf_round(x0,x1,16); tf_round(x0,x1,24);
    x0 += ks1; x1 += ks2 + 4u;
    tf_round(x0,x1,13); tf_round(x0,x1,15); tf_round(x0,x1,26); tf_round(x0,x1,6);
    x0 += ks2; x1 += ks0 + 5u;
    return make_uint2(x0, x1);
}

// ---- slot-direct scatter: one int atomic + one 8B store per edge ----------
__global__ void k_scatter_direct(const int* __restrict__ src, const int* __restrict__ dst,
                                 const float* __restrict__ w,
                                 int* __restrict__ cursor, int2* __restrict__ slots) {
    int e = blockIdx.x * blockDim.x + threadIdx.x;
    if (e < N_EDGES) {
        int d = dst[e];
        int pos = atomicAdd(&cursor[d], 1);
        if (pos < CAP)
            slots[((size_t)d << 6) + pos] = make_int2(src[e], __float_as_int(w[e]));
    }
}

// ---- deg + dis: wave per node, segmented reduce over slots ----------------
__launch_bounds__(256)
__global__ void k_deg(const int* __restrict__ cursor, const int2* __restrict__ slots,
                      float* __restrict__ dis) {
    int node = (blockIdx.x * blockDim.x + threadIdx.x) >> 6;
    int lane = threadIdx.x & 63;
    if (node >= N_NODES) return;
    int cnt = cursor[node]; cnt = cnt > CAP ? CAP : cnt;
    float wv = 0.f;
    if (lane < cnt) wv = __int_as_float(slots[((size_t)node << 6) + lane].y);
    #pragma unroll
    for (int d = 1; d < 64; d <<= 1) wv += __shfl_xor(wv, d, 64);
    if (lane == 0) dis[node] = rsqrtf(wv + 1.0f);   // +1 = self-loop weight
}

// ---- GEMM1 (bf16 MFMA): h1[100000,64] = x[100000,512] @ W1[512,64] --------
// 128 rows/block, 4 waves, each wave 32 rows x 64 cols = 2x4 16x16 frags.
// W1 staged once per block into LDS, pre-swizzled to B-fragment layout.
__launch_bounds__(256)
__global__ void k_gemm1(const float* __restrict__ x, const float* __restrict__ W1,
                        float* __restrict__ h1) {
    __shared__ bf16_t Wf[16 * 4 * 64 * 8];   // [kstep][cf][lane][elem] = 64 KB
    int tid = threadIdx.x;
    // stage + swizzle W1 (512x64 fp32 -> bf16 fragments)
    #pragma unroll 8
    for (int it = 0; it < 128; ++it) {
        int e = tid + 256 * it;              // e = k*64 + col
        int k = e >> 6, col = e & 63;
        float wv = W1[e];
        int kstep = k >> 5, g = (k >> 3) & 3, elem = k & 7;
        int cf = col >> 4, lane = (col & 15) | (g << 4);
        Wf[(((kstep << 2) + cf) << 9) + (lane << 3) + elem] = (bf16_t)wv;
    }
    __syncthreads();

    int w = tid >> 6, l = tid & 63;
    int r = l & 15, g = l >> 4;
    int wrow = blockIdx.x * 128 + w * 32;
    f32x4 acc[2][4] = {};
    const float* xp0 = x + (size_t)(wrow + r) * D_FEAT + 8 * g;
    const float* xp1 = x + (size_t)(wrow + 16 + r) * D_FEAT + 8 * g;
    bool ok0 = (wrow + r) < N_NODES;
    bool ok1 = (wrow + 16 + r) < N_NODES;

    #pragma unroll
    for (int t = 0; t < 16; ++t) {
        float4 p0 = make_float4(0.f,0.f,0.f,0.f), q0 = p0, p1 = p0, q1 = p0;
        if (ok0) {
            p0 = *(const float4*)(xp0 + t * 32);
            q0 = *(const float4*)(xp0 + t * 32 + 4);
        }
        if (ok1) {
            p1 = *(const float4*)(xp1 + t * 32);
            q1 = *(const float4*)(xp1 + t * 32 + 4);
        }
        bf16x8 a0, a1;
        a0[0]=(bf16_t)p0.x; a0[1]=(bf16_t)p0.y; a0[2]=(bf16_t)p0.z; a0[3]=(bf16_t)p0.w;
        a0[4]=(bf16_t)q0.x; a0[5]=(bf16_t)q0.y; a0[6]=(bf16_t)q0.z; a0[7]=(bf16_t)q0.w;
        a1[0]=(bf16_t)p1.x; a1[1]=(bf16_t)p1.y; a1[2]=(bf16_t)p1.z; a1[3]=(bf16_t)p1.w;
        a1[4]=(bf16_t)q1.x; a1[5]=(bf16_t)q1.y; a1[6]=(bf16_t)q1.z; a1[7]=(bf16_t)q1.w;
        #pragma unroll
        for (int cf = 0; cf < 4; ++cf) {
            bf16x8 b = *(const bf16x8*)&Wf[(((t << 2) + cf) << 9) + (l << 3)];
            acc[0][cf] = __builtin_amdgcn_mfma_f32_16x16x32_bf16(a0, b, acc[0][cf], 0, 0, 0);
            acc[1][cf] = __builtin_amdgcn_mfma_f32_16x16x32_bf16(a1, b, acc[1][cf], 0, 0, 0);
        }
    }
    // C/D layout: col = lane&15, row = 4*(lane>>4) + reg
    #pragma unroll
    for (int rf = 0; rf < 2; ++rf)
        #pragma unroll
        for (int cf = 0; cf < 4; ++cf)
            #pragma unroll
            for (int q = 0; q < 4; ++q) {
                int row = wrow + rf * 16 + 4 * g + q;
                int col = cf * 16 + r;
                if (row < N_NODES) h1[(size_t)row * HIDDEN + col] = acc[rf][cf][q];
            }
}

// ---- agg1 + bias + relu + exact-jax dropout (partitionable threefry) ------
__launch_bounds__(256)
__global__ void k_agg1(const float* __restrict__ h1, const int2* __restrict__ slots,
                       const int* __restrict__ cursor, const float* __restrict__ dis,
                       const float* __restrict__ b1, float* __restrict__ h2) {
    int i = (blockIdx.x * blockDim.x + threadIdx.x) >> 6;  // node id
    int f = threadIdx.x & 63;
    if (i >= N_NODES) return;
    float di = dis[i];
    float acc = di * di * h1[(size_t)i * HIDDEN + f];      // self loop (w=1)
    int cnt = cursor[i]; cnt = cnt > CAP ? CAP : cnt;
    const int2* sl = &slots[(size_t)i << 6];
    int p = 0;
    for (; p + 4 <= cnt; p += 4) {
        int2 e0 = sl[p], e1 = sl[p+1], e2 = sl[p+2], e3 = sl[p+3];
        float n0 = dis[e0.x] * __int_as_float(e0.y) * di;
        float n1 = dis[e1.x] * __int_as_float(e1.y) * di;
        float n2 = dis[e2.x] * __int_as_float(e2.y) * di;
        float n3 = dis[e3.x] * __int_as_float(e3.y) * di;
        float v0 = h1[(size_t)e0.x * HIDDEN + f];
        float v1 = h1[(size_t)e1.x * HIDDEN + f];
        float v2 = h1[(size_t)e2.x * HIDDEN + f];
        float v3 = h1[(size_t)e3.x * HIDDEN + f];
        acc += n0 * v0 + n1 * v1 + n2 * v2 + n3 * v3;
    }
    for (; p < cnt; ++p) {
        int2 e0 = sl[p];
        acc += dis[e0.x] * __int_as_float(e0.y) * di * h1[(size_t)e0.x * HIDDEN + f];
    }
    acc += b1[f];
    acc = fmaxf(acc, 0.f);
    // dropout: partitionable threefry, counter (0, idx), bits = x0^x1, keep iff MSB==0
    unsigned idx = (unsigned)i * HIDDEN + f;
    uint2 rr = threefry_0_42(0u, idx);
    unsigned bits = rr.x ^ rr.y;
    float v = (bits & 0x80000000u) ? 0.f : acc * 2.f;
    h2[(size_t)i * HIDDEN + f] = v;
}

// ---------------- GEMM2: g[100000,16] = h2 @ W2[64,16] ----------------------
__launch_bounds__(256)
__global__ void k_gemm2(const float* __restrict__ h2, const float* __restrict__ W2,
                        float* __restrict__ g) {
    __shared__ float Ws[HIDDEN * N_CLASS];
    int tid = threadIdx.x;
    #pragma unroll
    for (int t = 0; t < 4; t++) Ws[tid + 256 * t] = W2[tid + 256 * t];
    __syncthreads();
    int node = blockIdx.x * 16 + (tid >> 4);
    int j = tid & 15;
    if (node < N_NODES) {
        const float* hr = &h2[(size_t)node * HIDDEN];
        float acc = 0.f;
        #pragma unroll
        for (int f = 0; f < HIDDEN; f++) acc += hr[f] * Ws[f * N_CLASS + j];
        g[(size_t)node * N_CLASS + j] = acc;
    }
}

// ---- agg2 + bias + log_softmax + both outputs -----------------------------
__launch_bounds__(256)
__global__ void k_out(const float* __restrict__ g, const int2* __restrict__ slots,
                      const int* __restrict__ cursor, const float* __restrict__ dis,
                      const float* __restrict__ b2, float* __restrict__ out) {
    int i = (blockIdx.x * blockDim.x + threadIdx.x) >> 4;  // node id
    int j = threadIdx.x & 15;
    if (i >= N_NODES) return;
    float di = dis[i];
    float acc = di * di * g[(size_t)i * N_CLASS + j];
    int cnt = cursor[i]; cnt = cnt > CAP ? CAP : cnt;
    const int2* sl = &slots[(size_t)i << 6];
    int p = 0;
    for (; p + 2 <= cnt; p += 2) {
        int2 e0 = sl[p], e1 = sl[p+1];
        float n0 = dis[e0.x] * __int_as_float(e0.y) * di;
        float n1 = dis[e1.x] * __int_as_float(e1.y) * di;
        acc += n0 * g[(size_t)e0.x * N_CLASS + j] + n1 * g[(size_t)e1.x * N_CLASS + j];
    }
    for (; p < cnt; ++p) {
        int2 e0 = sl[p];
        acc += dis[e0.x] * __int_as_float(e0.y) * di * g[(size_t)e0.x * N_CLASS + j];
    }
    acc += b2[j];
    float xo = acc;
    float m = acc;
    #pragma unroll
    for (int d = 1; d < 16; d <<= 1) m = fmaxf(m, __shfl_xor(m, d, 16));
    float ex = expf(acc - m);
    float s = ex;
    #pragma unroll
    for (int d = 1; d < 16; d <<= 1) s += __shfl_xor(s, d, 16);
    float ls = (acc - m) - logf(s);
    out[(size_t)i * N_CLASS + j] = ls;
    out[(size_t)N_NODES * N_CLASS + (size_t)i * N_CLASS + j] = xo;
}

// ---------------------------------------------------------------------------
extern "C" void kernel_launch(void* const* d_in, const int* in_sizes, int n_in,
                              void* d_out, int out_size, void* d_ws, size_t ws_size,
                              hipStream_t stream) {
    const float* x  = (const float*)d_in[0];
    const int*   ei = (const int*)d_in[1];
    const float* ew = (const float*)d_in[2];
    const float* W1 = (const float*)d_in[3];
    const float* b1 = (const float*)d_in[4];
    const float* W2 = (const float*)d_in[5];
    const float* b2 = (const float*)d_in[6];
    float* out = (float*)d_out;
    const int* src = ei;
    const int* dst = ei + N_EDGES;

    size_t off = 0;
    char* wsb = (char*)d_ws;
    auto alloc = [&](size_t n) -> char* {
        char* p = wsb + off;
        off = (off + n + 255) & ~(size_t)255;
        return p;
    };
    int*   cursor = (int*)  alloc((size_t)N_NODES * 4);
    float* dis    = (float*)alloc((size_t)N_NODES * 4);
    int2*  slots  = (int2*) alloc((size_t)N_NODES * CAP * 8);   // 51.2 MB
    float* h1     = (float*)alloc((size_t)N_NODES * HIDDEN * 4);
    float* h2     = (float*)alloc((size_t)N_NODES * HIDDEN * 4);
    float* g      = (float*)alloc((size_t)N_NODES * N_CLASS * 4);

    hipMemsetAsync(cursor, 0, (size_t)N_NODES * 4, stream);

    k_scatter_direct<<<(N_EDGES + 255) / 256, 256, 0, stream>>>(src, dst, ew, cursor, slots);
    k_deg  <<<(N_NODES * 64 + 255) / 256, 256, 0, stream>>>(cursor, slots, dis);
    k_gemm1<<<(N_NODES + 127) / 128, 256, 0, stream>>>(x, W1, h1);
    k_agg1 <<<(N_NODES * 64 + 255) / 256, 256, 0, stream>>>(h1, slots, cursor, dis, b1, h2);
    k_gemm2<<<(N_NODES + 15) / 16, 256, 0, stream>>>(h2, W2, g);
    k_out  <<<(N_NODES * 16 + 255) / 256, 256, 0, stream>>>(g, slots, cursor, dis, b2, out);
}

// Round 5
// 250.396 us; speedup vs baseline: 2.0601x; 1.2915x over previous
//
#include <hip/hip_runtime.h>
#include <stdint.h>

#define N_NODES 100000
#define N_EDGES 1600000
#define D_FEAT  512
#define HIDDEN  64
#define N_CLASS 16
#define CAP     64          // fixed slot capacity per node (max in-deg ~45)
#define NBKT    196         // buckets of 512 nodes (dst>>9)
#define BCAP    10240       // per-bucket edge capacity (avg ~8163, >12 sigma margin)
#define EPB     4096        // edges per pass-1 block
#define NWG1    ((N_EDGES + EPB - 1) / EPB)   // 391

typedef __bf16 bf16_t;
typedef bf16_t bf16x8 __attribute__((ext_vector_type(8)));
typedef float  f32x4  __attribute__((ext_vector_type(4)));

// ---------------- threefry2x32-20, key = (0, 42)  (jax.random.key(42)) ------
__device__ __forceinline__ unsigned rotl32(unsigned x, int d) {
    return (x << d) | (x >> (32 - d));
}
__device__ __forceinline__ void tf_round(unsigned& x0, unsigned& x1, int r) {
    x0 += x1; x1 = rotl32(x1, r); x1 ^= x0;
}
__device__ __forceinline__ uint2 threefry_0_42(unsigned c0, unsigned c1) {
    const unsigned ks0 = 0u, ks1 = 42u, ks2 = 0x1BD11BDAu ^ 0u ^ 42u;
    unsigned x0 = c0 + ks0, x1 = c1 + ks1;
    tf_round(x0,x1,13); tf_round(x0,x1,15); tf_round(x0,x1,26); tf_round(x0,x1,6);
    x0 += ks1; x1 += ks2 + 1u;
    tf_round(x0,x1,17); tf_round(x0,x1,29); tf_round(x0,x1,16); tf_round(x0,x1,24);
    x0 += ks2; x1 += ks0 + 2u;
    tf_round(x0,x1,13); tf_round(x0,x1,15); tf_round(x0,x1,26); tf_round(x0,x1,6);
    x0 += ks0; x1 += ks1 + 3u;
    tf_round(x0,x1,17); tf_round(x0,x1,29); tf_round(x0,x1,16); tf_round(x0,x1,24);
    x0 += ks1; x1 += ks2 + 4u;
    tf_round(x0,x1,13); tf_round(x0,x1,15); tf_round(x0,x1,26); tf_round(x0,x1,6);
    x0 += ks2; x1 += ks0 + 5u;
    return make_uint2(x0, x1);
}

// ---- pass 1: bin edges by dst>>9 into per-bucket contiguous ranges --------
__launch_bounds__(256)
__global__ void k_bin(const int* __restrict__ src, const int* __restrict__ dst,
                      const float* __restrict__ w,
                      int* __restrict__ bucket_cursor, int2* __restrict__ bkt) {
    __shared__ int hist[NBKT];
    __shared__ int binbase[NBKT];
    __shared__ int bincur[NBKT];
    int tid = threadIdx.x;
    int c4 = blockIdx.x * (EPB / 4);            // int4 base index
    for (int t = tid; t < NBKT; t += 256) { hist[t] = 0; bincur[t] = 0; }
    __syncthreads();
    // phase A: LDS histogram of buckets
    #pragma unroll
    for (int i = 0; i < EPB / 1024; ++i) {
        int e4 = c4 + tid + 256 * i;
        if (e4 * 4 < N_EDGES) {
            int4 d = ((const int4*)dst)[e4];
            atomicAdd(&hist[d.x >> 9], 1);
            atomicAdd(&hist[d.y >> 9], 1);
            atomicAdd(&hist[d.z >> 9], 1);
            atomicAdd(&hist[d.w >> 9], 1);
        }
    }
    __syncthreads();
    // phase B: one global atomic per (wg,bucket) to reserve a disjoint range
    for (int t = tid; t < NBKT; t += 256)
        binbase[t] = hist[t] ? atomicAdd(&bucket_cursor[t], hist[t]) : 0;
    __syncthreads();
    // phase C: scatter packed records into reserved ranges
    #pragma unroll
    for (int i = 0; i < EPB / 1024; ++i) {
        int e4 = c4 + tid + 256 * i;
        if (e4 * 4 < N_EDGES) {
            int4 s  = ((const int4*)src)[e4];
            int4 d  = ((const int4*)dst)[e4];
            int4 wv = ((const int4*)w)[e4];
            int ss[4] = {s.x, s.y, s.z, s.w};
            int dd[4] = {d.x, d.y, d.z, d.w};
            int ww[4] = {wv.x, wv.y, wv.z, wv.w};
            #pragma unroll
            for (int q = 0; q < 4; ++q) {
                int b = dd[q] >> 9;
                int rank = atomicAdd(&bincur[b], 1);
                int pos = binbase[b] + rank;
                if (pos < BCAP)
                    bkt[(size_t)b * BCAP + pos] =
                        make_int2(ss[q] | ((dd[q] & 511) << 17), ww[q]);
            }
        }
    }
}

// ---- pass 2: per-bucket slot build + weighted degree + dis ----------------
__launch_bounds__(256)
__global__ void k_build(const int* __restrict__ bucket_cursor, const int2* __restrict__ bkt,
                        int2* __restrict__ slots, int* __restrict__ cursor,
                        float* __restrict__ dis) {
    __shared__ int   cur[512];
    __shared__ float dg[512];
    int b = blockIdx.x, tid = threadIdx.x;
    cur[tid] = 0; cur[tid + 256] = 0;
    dg[tid] = 0.f; dg[tid + 256] = 0.f;
    __syncthreads();
    int cnt = bucket_cursor[b]; if (cnt > BCAP) cnt = BCAP;
    for (int e = tid; e < cnt; e += 256) {
        int2 p = bkt[(size_t)b * BCAP + e];
        int dl = ((unsigned)p.x) >> 17;
        int s  = p.x & 0x1FFFF;
        int rank = atomicAdd(&cur[dl], 1);
        if (rank < CAP)
            slots[((((size_t)b << 9) | dl) << 6) + rank] = make_int2(s, p.y);
        atomicAdd(&dg[dl], __int_as_float(p.y));
    }
    __syncthreads();
    #pragma unroll
    for (int t = 0; t < 2; ++t) {
        int loc = tid + 256 * t;
        int node = (b << 9) + loc;
        if (node < N_NODES) {
            cursor[node] = cur[loc];
            dis[node] = rsqrtf(dg[loc] + 1.0f);   // +1 = self-loop weight
        }
    }
}

// ---- GEMM1 (bf16 MFMA): h1[100000,64] = x[100000,512] @ W1[512,64] --------
__launch_bounds__(256)
__global__ void k_gemm1(const float* __restrict__ x, const float* __restrict__ W1,
                        float* __restrict__ h1) {
    __shared__ bf16_t Wf[16 * 4 * 64 * 8];   // [kstep][cf][lane][elem] = 64 KB
    int tid = threadIdx.x;
    #pragma unroll 8
    for (int it = 0; it < 128; ++it) {
        int e = tid + 256 * it;              // e = k*64 + col
        int k = e >> 6, col = e & 63;
        float wv = W1[e];
        int kstep = k >> 5, g = (k >> 3) & 3, elem = k & 7;
        int cf = col >> 4, lane = (col & 15) | (g << 4);
        Wf[(((kstep << 2) + cf) << 9) + (lane << 3) + elem] = (bf16_t)wv;
    }
    __syncthreads();

    int w = tid >> 6, l = tid & 63;
    int r = l & 15, g = l >> 4;
    int wrow = blockIdx.x * 128 + w * 32;
    f32x4 acc[2][4] = {};
    const float* xp0 = x + (size_t)(wrow + r) * D_FEAT + 8 * g;
    const float* xp1 = x + (size_t)(wrow + 16 + r) * D_FEAT + 8 * g;
    bool ok0 = (wrow + r) < N_NODES;
    bool ok1 = (wrow + 16 + r) < N_NODES;

    #pragma unroll
    for (int t = 0; t < 16; ++t) {
        float4 p0 = make_float4(0.f,0.f,0.f,0.f), q0 = p0, p1 = p0, q1 = p0;
        if (ok0) {
            p0 = *(const float4*)(xp0 + t * 32);
            q0 = *(const float4*)(xp0 + t * 32 + 4);
        }
        if (ok1) {
            p1 = *(const float4*)(xp1 + t * 32);
            q1 = *(const float4*)(xp1 + t * 32 + 4);
        }
        bf16x8 a0, a1;
        a0[0]=(bf16_t)p0.x; a0[1]=(bf16_t)p0.y; a0[2]=(bf16_t)p0.z; a0[3]=(bf16_t)p0.w;
        a0[4]=(bf16_t)q0.x; a0[5]=(bf16_t)q0.y; a0[6]=(bf16_t)q0.z; a0[7]=(bf16_t)q0.w;
        a1[0]=(bf16_t)p1.x; a1[1]=(bf16_t)p1.y; a1[2]=(bf16_t)p1.z; a1[3]=(bf16_t)p1.w;
        a1[4]=(bf16_t)q1.x; a1[5]=(bf16_t)q1.y; a1[6]=(bf16_t)q1.z; a1[7]=(bf16_t)q1.w;
        #pragma unroll
        for (int cf = 0; cf < 4; ++cf) {
            bf16x8 b = *(const bf16x8*)&Wf[(((t << 2) + cf) << 9) + (l << 3)];
            acc[0][cf] = __builtin_amdgcn_mfma_f32_16x16x32_bf16(a0, b, acc[0][cf], 0, 0, 0);
            acc[1][cf] = __builtin_amdgcn_mfma_f32_16x16x32_bf16(a1, b, acc[1][cf], 0, 0, 0);
        }
    }
    // C/D layout: col = lane&15, row = 4*(lane>>4) + reg
    #pragma unroll
    for (int rf = 0; rf < 2; ++rf)
        #pragma unroll
        for (int cf = 0; cf < 4; ++cf)
            #pragma unroll
            for (int q = 0; q < 4; ++q) {
                int row = wrow + rf * 16 + 4 * g + q;
                int col = cf * 16 + r;
                if (row < N_NODES) h1[(size_t)row * HIDDEN + col] = acc[rf][cf][q];
            }
}

// ---- agg1 + bias + relu + exact-jax dropout (partitionable threefry) ------
__launch_bounds__(256)
__global__ void k_agg1(const float* __restrict__ h1, const int2* __restrict__ slots,
                       const int* __restrict__ cursor, const float* __restrict__ dis,
                       const float* __restrict__ b1, float* __restrict__ h2) {
    int i = (blockIdx.x * blockDim.x + threadIdx.x) >> 6;  // node id
    int f = threadIdx.x & 63;
    if (i >= N_NODES) return;
    float di = dis[i];
    float acc = di * di * h1[(size_t)i * HIDDEN + f];      // self loop (w=1)
    int cnt = cursor[i]; cnt = cnt > CAP ? CAP : cnt;
    const int2* sl = &slots[(size_t)i << 6];
    int p = 0;
    for (; p + 4 <= cnt; p += 4) {
        int2 e0 = sl[p], e1 = sl[p+1], e2 = sl[p+2], e3 = sl[p+3];
        float n0 = dis[e0.x] * __int_as_float(e0.y) * di;
        float n1 = dis[e1.x] * __int_as_float(e1.y) * di;
        float n2 = dis[e2.x] * __int_as_float(e2.y) * di;
        float n3 = dis[e3.x] * __int_as_float(e3.y) * di;
        float v0 = h1[(size_t)e0.x * HIDDEN + f];
        float v1 = h1[(size_t)e1.x * HIDDEN + f];
        float v2 = h1[(size_t)e2.x * HIDDEN + f];
        float v3 = h1[(size_t)e3.x * HIDDEN + f];
        acc += n0 * v0 + n1 * v1 + n2 * v2 + n3 * v3;
    }
    for (; p < cnt; ++p) {
        int2 e0 = sl[p];
        acc += dis[e0.x] * __int_as_float(e0.y) * di * h1[(size_t)e0.x * HIDDEN + f];
    }
    acc += b1[f];
    acc = fmaxf(acc, 0.f);
    // dropout: partitionable threefry, counter (0, idx), bits = x0^x1, keep iff MSB==0
    unsigned idx = (unsigned)i * HIDDEN + f;
    uint2 rr = threefry_0_42(0u, idx);
    unsigned bits = rr.x ^ rr.y;
    float v = (bits & 0x80000000u) ? 0.f : acc * 2.f;
    h2[(size_t)i * HIDDEN + f] = v;
}

// ---------------- GEMM2: g[100000,16] = h2 @ W2[64,16] ----------------------
__launch_bounds__(256)
__global__ void k_gemm2(const float* __restrict__ h2, const float* __restrict__ W2,
                        float* __restrict__ g) {
    __shared__ float Ws[HIDDEN * N_CLASS];
    int tid = threadIdx.x;
    #pragma unroll
    for (int t = 0; t < 4; t++) Ws[tid + 256 * t] = W2[tid + 256 * t];
    __syncthreads();
    int node = blockIdx.x * 16 + (tid >> 4);
    int j = tid & 15;
    if (node < N_NODES) {
        const float* hr = &h2[(size_t)node * HIDDEN];
        float acc = 0.f;
        #pragma unroll
        for (int f = 0; f < HIDDEN; f++) acc += hr[f] * Ws[f * N_CLASS + j];
        g[(size_t)node * N_CLASS + j] = acc;
    }
}

// ---- agg2 + bias + log_softmax + both outputs -----------------------------
__launch_bounds__(256)
__global__ void k_out(const float* __restrict__ g, const int2* __restrict__ slots,
                      const int* __restrict__ cursor, const float* __restrict__ dis,
                      const float* __restrict__ b2, float* __restrict__ out) {
    int i = (blockIdx.x * blockDim.x + threadIdx.x) >> 4;  // node id
    int j = threadIdx.x & 15;
    if (i >= N_NODES) return;
    float di = dis[i];
    float acc = di * di * g[(size_t)i * N_CLASS + j];
    int cnt = cursor[i]; cnt = cnt > CAP ? CAP : cnt;
    const int2* sl = &slots[(size_t)i << 6];
    int p = 0;
    for (; p + 2 <= cnt; p += 2) {
        int2 e0 = sl[p], e1 = sl[p+1];
        float n0 = dis[e0.x] * __int_as_float(e0.y) * di;
        float n1 = dis[e1.x] * __int_as_float(e1.y) * di;
        acc += n0 * g[(size_t)e0.x * N_CLASS + j] + n1 * g[(size_t)e1.x * N_CLASS + j];
    }
    for (; p < cnt; ++p) {
        int2 e0 = sl[p];
        acc += dis[e0.x] * __int_as_float(e0.y) * di * g[(size_t)e0.x * N_CLASS + j];
    }
    acc += b2[j];
    float xo = acc;
    float m = acc;
    #pragma unroll
    for (int d = 1; d < 16; d <<= 1) m = fmaxf(m, __shfl_xor(m, d, 16));
    float ex = expf(acc - m);
    float s = ex;
    #pragma unroll
    for (int d = 1; d < 16; d <<= 1) s += __shfl_xor(s, d, 16);
    float ls = (acc - m) - logf(s);
    out[(size_t)i * N_CLASS + j] = ls;
    out[(size_t)N_NODES * N_CLASS + (size_t)i * N_CLASS + j] = xo;
}

// ---------------------------------------------------------------------------
extern "C" void kernel_launch(void* const* d_in, const int* in_sizes, int n_in,
                              void* d_out, int out_size, void* d_ws, size_t ws_size,
                              hipStream_t stream) {
    const float* x  = (const float*)d_in[0];
    const int*   ei = (const int*)d_in[1];
    const float* ew = (const float*)d_in[2];
    const float* W1 = (const float*)d_in[3];
    const float* b1 = (const float*)d_in[4];
    const float* W2 = (const float*)d_in[5];
    const float* b2 = (const float*)d_in[6];
    float* out = (float*)d_out;
    const int* src = ei;
    const int* dst = ei + N_EDGES;

    size_t off = 0;
    char* wsb = (char*)d_ws;
    auto alloc = [&](size_t n) -> char* {
        char* p = wsb + off;
        off = (off + n + 255) & ~(size_t)255;
        return p;
    };
    int*   cursor = (int*)  alloc((size_t)N_NODES * 4);
    float* dis    = (float*)alloc((size_t)N_NODES * 4);
    int*   bcur   = (int*)  alloc(NBKT * 4);
    int2*  slots  = (int2*) alloc((size_t)N_NODES * CAP * 8);   // 51.2 MB
    float* h1     = (float*)alloc((size_t)N_NODES * HIDDEN * 4);
    float* h2     = (float*)alloc((size_t)N_NODES * HIDDEN * 4);
    float* g      = (float*)alloc((size_t)N_NODES * N_CLASS * 4);
    int2*  bkt    = (int2*)h2;   // alias: bkt (16.1 MB) consumed before h2 written

    hipMemsetAsync(bcur, 0, NBKT * 4, stream);

    k_bin  <<<NWG1, 256, 0, stream>>>(src, dst, ew, bcur, bkt);
    k_build<<<NBKT, 256, 0, stream>>>(bcur, bkt, slots, cursor, dis);
    k_gemm1<<<(N_NODES + 127) / 128, 256, 0, stream>>>(x, W1, h1);
    k_agg1 <<<(N_NODES * 64 + 255) / 256, 256, 0, stream>>>(h1, slots, cursor, dis, b1, h2);
    k_gemm2<<<(N_NODES + 15) / 16, 256, 0, stream>>>(h2, W2, g);
    k_out  <<<(N_NODES * 16 + 255) / 256, 256, 0, stream>>>(g, slots, cursor, dis, b2, out);
}

// Round 6
// 223.667 us; speedup vs baseline: 2.3063x; 1.1195x over previous
//
#include <hip/hip_runtime.h>
#include <stdint.h>

#define N_NODES 100000
#define N_EDGES 1600000
#define D_FEAT  512
#define HIDDEN  64
#define N_CLASS 16
#define CAP     64          // fixed slot capacity per node (max in-deg ~45)
#define NBKT    196         // buckets of 512 nodes (dst>>9)
#define BCAP    10240       // per-bucket edge capacity (avg ~8163, >12 sigma margin)
#define EPB     4096        // edges per pass-1 block
#define NWG1    ((N_EDGES + EPB - 1) / EPB)   // 391

typedef __bf16 bf16_t;
typedef bf16_t bf16x8 __attribute__((ext_vector_type(8)));
typedef float  f32x4  __attribute__((ext_vector_type(4)));

// ---------------- threefry2x32-20, key = (0, 42)  (jax.random.key(42)) ------
__device__ __forceinline__ unsigned rotl32(unsigned x, int d) {
    return (x << d) | (x >> (32 - d));
}
__device__ __forceinline__ void tf_round(unsigned& x0, unsigned& x1, int r) {
    x0 += x1; x1 = rotl32(x1, r); x1 ^= x0;
}
__device__ __forceinline__ uint2 threefry_0_42(unsigned c0, unsigned c1) {
    const unsigned ks0 = 0u, ks1 = 42u, ks2 = 0x1BD11BDAu ^ 0u ^ 42u;
    unsigned x0 = c0 + ks0, x1 = c1 + ks1;
    tf_round(x0,x1,13); tf_round(x0,x1,15); tf_round(x0,x1,26); tf_round(x0,x1,6);
    x0 += ks1; x1 += ks2 + 1u;
    tf_round(x0,x1,17); tf_round(x0,x1,29); tf_round(x0,x1,16); tf_round(x0,x1,24);
    x0 += ks2; x1 += ks0 + 2u;
    tf_round(x0,x1,13); tf_round(x0,x1,15); tf_round(x0,x1,26); tf_round(x0,x1,6);
    x0 += ks0; x1 += ks1 + 3u;
    tf_round(x0,x1,17); tf_round(x0,x1,29); tf_round(x0,x1,16); tf_round(x0,x1,24);
    x0 += ks1; x1 += ks2 + 4u;
    tf_round(x0,x1,13); tf_round(x0,x1,15); tf_round(x0,x1,26); tf_round(x0,x1,6);
    x0 += ks2; x1 += ks0 + 5u;
    return make_uint2(x0, x1);
}

// ---- pass 1: bin edges by dst>>9 into per-bucket contiguous ranges --------
__launch_bounds__(256)
__global__ void k_bin(const int* __restrict__ src, const int* __restrict__ dst,
                      const float* __restrict__ w,
                      int* __restrict__ bucket_cursor, int2* __restrict__ bkt) {
    __shared__ int hist[NBKT];
    __shared__ int binbase[NBKT];
    __shared__ int bincur[NBKT];
    int tid = threadIdx.x;
    int c4 = blockIdx.x * (EPB / 4);            // int4 base index
    for (int t = tid; t < NBKT; t += 256) { hist[t] = 0; bincur[t] = 0; }
    __syncthreads();
    #pragma unroll
    for (int i = 0; i < EPB / 1024; ++i) {
        int e4 = c4 + tid + 256 * i;
        if (e4 * 4 < N_EDGES) {
            int4 d = ((const int4*)dst)[e4];
            atomicAdd(&hist[d.x >> 9], 1);
            atomicAdd(&hist[d.y >> 9], 1);
            atomicAdd(&hist[d.z >> 9], 1);
            atomicAdd(&hist[d.w >> 9], 1);
        }
    }
    __syncthreads();
    for (int t = tid; t < NBKT; t += 256)
        binbase[t] = hist[t] ? atomicAdd(&bucket_cursor[t], hist[t]) : 0;
    __syncthreads();
    #pragma unroll
    for (int i = 0; i < EPB / 1024; ++i) {
        int e4 = c4 + tid + 256 * i;
        if (e4 * 4 < N_EDGES) {
            int4 s  = ((const int4*)src)[e4];
            int4 d  = ((const int4*)dst)[e4];
            int4 wv = ((const int4*)w)[e4];
            int ss[4] = {s.x, s.y, s.z, s.w};
            int dd[4] = {d.x, d.y, d.z, d.w};
            int ww[4] = {wv.x, wv.y, wv.z, wv.w};
            #pragma unroll
            for (int q = 0; q < 4; ++q) {
                int b = dd[q] >> 9;
                int rank = atomicAdd(&bincur[b], 1);
                int pos = binbase[b] + rank;
                if (pos < BCAP)
                    bkt[(size_t)b * BCAP + pos] =
                        make_int2(ss[q] | ((dd[q] & 511) << 17), ww[q]);
            }
        }
    }
}

// ---- pass 2: per-bucket slot build + weighted degree + dis ----------------
__launch_bounds__(256)
__global__ void k_build(const int* __restrict__ bucket_cursor, const int2* __restrict__ bkt,
                        int2* __restrict__ slots, int* __restrict__ cursor,
                        float* __restrict__ dis) {
    __shared__ int   cur[512];
    __shared__ float dg[512];
    int b = blockIdx.x, tid = threadIdx.x;
    cur[tid] = 0; cur[tid + 256] = 0;
    dg[tid] = 0.f; dg[tid + 256] = 0.f;
    __syncthreads();
    int cnt = bucket_cursor[b]; if (cnt > BCAP) cnt = BCAP;
    for (int e = tid; e < cnt; e += 256) {
        int2 p = bkt[(size_t)b * BCAP + e];
        int dl = ((unsigned)p.x) >> 17;
        int s  = p.x & 0x1FFFF;
        int rank = atomicAdd(&cur[dl], 1);
        if (rank < CAP)
            slots[((((size_t)b << 9) | dl) << 6) + rank] = make_int2(s, p.y);
        atomicAdd(&dg[dl], __int_as_float(p.y));
    }
    __syncthreads();
    #pragma unroll
    for (int t = 0; t < 2; ++t) {
        int loc = tid + 256 * t;
        int node = (b << 9) + loc;
        if (node < N_NODES) {
            cursor[node] = cur[loc];
            dis[node] = rsqrtf(dg[loc] + 1.0f);   // +1 = self-loop weight
        }
    }
}

// ---- prep: W1 (512x64 fp32) -> swizzled bf16 B-fragment layout (64 KB) ----
// index: e = k*64+col; kstep=k>>5, g=(k>>3)&3, e8=k&7; cf=col>>4, lane=(col&15)|(g<<4)
__global__ void k_prepw(const float* __restrict__ W1, bf16_t* __restrict__ Wfg) {
    int e = blockIdx.x * 256 + threadIdx.x;     // grid 128 -> 32768 elems
    int k = e >> 6, col = e & 63;
    int kstep = k >> 5, gg = (k >> 3) & 3, e8 = k & 7;
    int cf = col >> 4, lane = (col & 15) | (gg << 4);
    Wfg[(((kstep << 2) + cf) << 9) + (lane << 3) + e8] = (bf16_t)W1[e];
}

// ---- GEMM1 (bf16 MFMA): h1[100000,64] = x[100000,512] @ W1[512,64] --------
// 128 rows/block, 4 waves, wave = 32 rows x 64 cols = 2x4 16x16x32 frags.
// W1 pre-swizzled in global (k_prepw); staged in two 32 KB halves -> LDS 32 KB.
__launch_bounds__(256)
__global__ void k_gemm1(const float* __restrict__ x, const bf16_t* __restrict__ Wfg,
                        float* __restrict__ h1) {
    __shared__ bf16_t Wf[16384];   // 32 KB: [t2:8][cf:4][lane:64][e:8]
    int tid = threadIdx.x;
    int w = tid >> 6, l = tid & 63;
    int r = l & 15, g = l >> 4;
    int wrow = blockIdx.x * 128 + w * 32;
    f32x4 acc[2][4] = {};
    const float* xp0 = x + (size_t)(wrow + r) * D_FEAT + 8 * g;
    const float* xp1 = x + (size_t)(wrow + 16 + r) * D_FEAT + 8 * g;
    bool ok0 = (wrow + r) < N_NODES;
    bool ok1 = (wrow + 16 + r) < N_NODES;

    #pragma unroll
    for (int h = 0; h < 2; ++h) {
        if (h) __syncthreads();             // all waves done reading half 0
        {
            const int4* sW = (const int4*)(Wfg + h * 16384);
            int4* dW = (int4*)Wf;
            #pragma unroll
            for (int t = 0; t < 8; ++t) dW[tid + 256 * t] = sW[tid + 256 * t];
        }
        __syncthreads();
        #pragma unroll
        for (int t2 = 0; t2 < 8; ++t2) {
            int t = h * 8 + t2;
            float4 p0 = make_float4(0.f,0.f,0.f,0.f), q0 = p0, p1 = p0, q1 = p0;
            if (ok0) {
                p0 = *(const float4*)(xp0 + t * 32);
                q0 = *(const float4*)(xp0 + t * 32 + 4);
            }
            if (ok1) {
                p1 = *(const float4*)(xp1 + t * 32);
                q1 = *(const float4*)(xp1 + t * 32 + 4);
            }
            bf16x8 a0, a1;
            a0[0]=(bf16_t)p0.x; a0[1]=(bf16_t)p0.y; a0[2]=(bf16_t)p0.z; a0[3]=(bf16_t)p0.w;
            a0[4]=(bf16_t)q0.x; a0[5]=(bf16_t)q0.y; a0[6]=(bf16_t)q0.z; a0[7]=(bf16_t)q0.w;
            a1[0]=(bf16_t)p1.x; a1[1]=(bf16_t)p1.y; a1[2]=(bf16_t)p1.z; a1[3]=(bf16_t)p1.w;
            a1[4]=(bf16_t)q1.x; a1[5]=(bf16_t)q1.y; a1[6]=(bf16_t)q1.z; a1[7]=(bf16_t)q1.w;
            #pragma unroll
            for (int cf = 0; cf < 4; ++cf) {
                bf16x8 b = *(const bf16x8*)&Wf[(((t2 << 2) + cf) << 9) + (l << 3)];
                acc[0][cf] = __builtin_amdgcn_mfma_f32_16x16x32_bf16(a0, b, acc[0][cf], 0, 0, 0);
                acc[1][cf] = __builtin_amdgcn_mfma_f32_16x16x32_bf16(a1, b, acc[1][cf], 0, 0, 0);
            }
        }
    }
    // C/D layout: col = lane&15, row = 4*(lane>>4) + reg
    #pragma unroll
    for (int rf = 0; rf < 2; ++rf)
        #pragma unroll
        for (int cf = 0; cf < 4; ++cf)
            #pragma unroll
            for (int q = 0; q < 4; ++q) {
                int row = wrow + rf * 16 + 4 * g + q;
                int col = cf * 16 + r;
                if (row < N_NODES) h1[(size_t)row * HIDDEN + col] = acc[rf][cf][q];
            }
}

// ---- fused agg1 + bias + relu + dropout + gemm2 ---------------------------
// Block = 4 nodes (wave per node). Phase 1: per-lane feature aggregation -> h2
// in LDS. Phase 2: g = h2 @ W2 (16 FMA/thread + 2 shfl_xor folds).
__launch_bounds__(256)
__global__ void k_agg1(const float* __restrict__ h1, const int2* __restrict__ slots,
                       const int* __restrict__ cursor, const float* __restrict__ dis,
                       const float* __restrict__ b1, const float* __restrict__ W2,
                       float* __restrict__ g) {
    __shared__ float W2s[HIDDEN * 17];   // padded rows: bank-conflict-light
    __shared__ float h2s[4][HIDDEN];
    int tid = threadIdx.x;
    #pragma unroll
    for (int t = 0; t < 4; ++t) {
        int e = tid + 256 * t;
        W2s[(e >> 4) * 17 + (e & 15)] = W2[e];
    }
    int i = (blockIdx.x * blockDim.x + tid) >> 6;  // node id
    int f = tid & 63;
    int w = tid >> 6;
    float val = 0.f;
    if (i < N_NODES) {
        float di = dis[i];
        float acc = di * di * h1[(size_t)i * HIDDEN + f];  // self loop (w=1)
        int cnt = cursor[i]; cnt = cnt > CAP ? CAP : cnt;
        const int2* sl = &slots[(size_t)i << 6];
        int p = 0;
        for (; p + 4 <= cnt; p += 4) {
            int2 e0 = sl[p], e1 = sl[p+1], e2 = sl[p+2], e3 = sl[p+3];
            float n0 = dis[e0.x] * __int_as_float(e0.y) * di;
            float n1 = dis[e1.x] * __int_as_float(e1.y) * di;
            float n2 = dis[e2.x] * __int_as_float(e2.y) * di;
            float n3 = dis[e3.x] * __int_as_float(e3.y) * di;
            float v0 = h1[(size_t)e0.x * HIDDEN + f];
            float v1 = h1[(size_t)e1.x * HIDDEN + f];
            float v2 = h1[(size_t)e2.x * HIDDEN + f];
            float v3 = h1[(size_t)e3.x * HIDDEN + f];
            acc += n0 * v0 + n1 * v1 + n2 * v2 + n3 * v3;
        }
        for (; p < cnt; ++p) {
            int2 e0 = sl[p];
            acc += dis[e0.x] * __int_as_float(e0.y) * di * h1[(size_t)e0.x * HIDDEN + f];
        }
        acc += b1[f];
        acc = fmaxf(acc, 0.f);
        // dropout: partitionable threefry, counter (0,idx), bits=x0^x1, keep iff MSB==0
        unsigned idx = (unsigned)i * HIDDEN + f;
        uint2 rr = threefry_0_42(0u, idx);
        unsigned bits = rr.x ^ rr.y;
        val = (bits & 0x80000000u) ? 0.f : acc * 2.f;
    }
    h2s[w][f] = val;
    __syncthreads();
    // phase 2: g[node][j] = sum_f h2[f] * W2[f][j]
    int j = tid & 15, q = (tid >> 4) & 3;
    int node = blockIdx.x * 4 + w;
    float p = 0.f;
    #pragma unroll
    for (int ff = 0; ff < 16; ++ff) {
        int fr = q * 16 + ff;
        p += h2s[w][fr] * W2s[fr * 17 + j];
    }
    p += __shfl_xor(p, 16, 64);
    p += __shfl_xor(p, 32, 64);
    if (q == 0 && node < N_NODES) g[(size_t)node * N_CLASS + j] = p;
}

// ---- agg2 + bias + log_softmax + both outputs -----------------------------
__launch_bounds__(256)
__global__ void k_out(const float* __restrict__ g, const int2* __restrict__ slots,
                      const int* __restrict__ cursor, const float* __restrict__ dis,
                      const float* __restrict__ b2, float* __restrict__ out) {
    int i = (blockIdx.x * blockDim.x + threadIdx.x) >> 4;  // node id
    int j = threadIdx.x & 15;
    if (i >= N_NODES) return;
    float di = dis[i];
    float acc = di * di * g[(size_t)i * N_CLASS + j];
    int cnt = cursor[i]; cnt = cnt > CAP ? CAP : cnt;
    const int2* sl = &slots[(size_t)i << 6];
    int p = 0;
    for (; p + 2 <= cnt; p += 2) {
        int2 e0 = sl[p], e1 = sl[p+1];
        float n0 = dis[e0.x] * __int_as_float(e0.y) * di;
        float n1 = dis[e1.x] * __int_as_float(e1.y) * di;
        acc += n0 * g[(size_t)e0.x * N_CLASS + j] + n1 * g[(size_t)e1.x * N_CLASS + j];
    }
    for (; p < cnt; ++p) {
        int2 e0 = sl[p];
        acc += dis[e0.x] * __int_as_float(e0.y) * di * g[(size_t)e0.x * N_CLASS + j];
    }
    acc += b2[j];
    float xo = acc;
    float m = acc;
    #pragma unroll
    for (int d = 1; d < 16; d <<= 1) m = fmaxf(m, __shfl_xor(m, d, 16));
    float ex = expf(acc - m);
    float s = ex;
    #pragma unroll
    for (int d = 1; d < 16; d <<= 1) s += __shfl_xor(s, d, 16);
    float ls = (acc - m) - logf(s);
    out[(size_t)i * N_CLASS + j] = ls;
    out[(size_t)N_NODES * N_CLASS + (size_t)i * N_CLASS + j] = xo;
}

// ---------------------------------------------------------------------------
extern "C" void kernel_launch(void* const* d_in, const int* in_sizes, int n_in,
                              void* d_out, int out_size, void* d_ws, size_t ws_size,
                              hipStream_t stream) {
    const float* x  = (const float*)d_in[0];
    const int*   ei = (const int*)d_in[1];
    const float* ew = (const float*)d_in[2];
    const float* W1 = (const float*)d_in[3];
    const float* b1 = (const float*)d_in[4];
    const float* W2 = (const float*)d_in[5];
    const float* b2 = (const float*)d_in[6];
    float* out = (float*)d_out;
    const int* src = ei;
    const int* dst = ei + N_EDGES;

    size_t off = 0;
    char* wsb = (char*)d_ws;
    auto alloc = [&](size_t n) -> char* {
        char* p = wsb + off;
        off = (off + n + 255) & ~(size_t)255;
        return p;
    };
    int*    cursor = (int*)   alloc((size_t)N_NODES * 4);
    float*  dis    = (float*) alloc((size_t)N_NODES * 4);
    int*    bcur   = (int*)   alloc(NBKT * 4);
    bf16_t* Wfg    = (bf16_t*)alloc(32768 * 2);                  // 64 KB
    int2*   slots  = (int2*)  alloc((size_t)N_NODES * CAP * 8);  // 51.2 MB
    float*  h1     = (float*) alloc((size_t)N_NODES * HIDDEN * 4);
    int2*   bkt    = (int2*)  alloc((size_t)NBKT * BCAP * 8);    // 16.1 MB
    float*  g      = (float*) alloc((size_t)N_NODES * N_CLASS * 4);

    hipMemsetAsync(bcur, 0, NBKT * 4, stream);

    k_prepw<<<128, 256, 0, stream>>>(W1, Wfg);
    k_bin  <<<NWG1, 256, 0, stream>>>(src, dst, ew, bcur, bkt);
    k_build<<<NBKT, 256, 0, stream>>>(bcur, bkt, slots, cursor, dis);
    k_gemm1<<<(N_NODES + 127) / 128, 256, 0, stream>>>(x, Wfg, h1);
    k_agg1 <<<(N_NODES + 3) / 4, 256, 0, stream>>>(h1, slots, cursor, dis, b1, W2, g);
    k_out  <<<(N_NODES * 16 + 255) / 256, 256, 0, stream>>>(g, slots, cursor, dis, b2, out);
}